// Round 7
// baseline (2672.706 us; speedup 1.0000x reference)
//
#include <hip/hip_runtime.h>
#include <hip/hip_bf16.h>

// HypLoRA: out = x@W^T + b + 2 * scale2(row) * (u(row) @ B)
//   u(row)    = s1 * (x_row @ A), s1 = min(||x||,1.5)/max(||x||,EPS)
//   scale2    = min(n2,1.5)/max(n2,EPS),  n2^2 = u^T (B B^T) u
// K = clip(exp(log_K),...) cancels identically in log(exp(.)) at origin.
//
// Launch 1 (k_prep): G = B B^T | per-row u = s1*(x@A) + x->bf16 | W->bf16
// Launch 2 (k_gemm): 256x256 tile, BK=32, TWO 32KB LDS buffers (64KB/block ->
// 2 blocks/CU co-resident: inter-block TLP hides vmcnt/barrier stalls, the
// m97/m114 mechanism round 5/6 lacked at 128KB). Round-5 phase template.

#define DD 4096
#define MR 8192
#define BM 256
#define BN 256

typedef float f32x4 __attribute__((ext_vector_type(4)));
typedef __bf16 bf16x8 __attribute__((ext_vector_type(8)));

#define GLOAD_LDS16(gptr, lptr)                                                        \
  __builtin_amdgcn_global_load_lds((const __attribute__((address_space(1))) void*)(gptr), \
                                   (__attribute__((address_space(3))) void*)(lptr), 16, 0, 0)

__device__ __forceinline__ __bf16 f2bf(float f) { return (__bf16)f; }

// ---------------- fused prep ----------------
// bid 0                  : G = B B^T (8x8)
// bid [1, 1+8192)        : row r: u[r] = s1 * (x_r @ A); Xb = bf16(x)  (round-5
//                          coalesced pattern: lane-consecutive d -> consecutive
//                          32B A-rows; round-6 "vectorized" variant regressed)
// bid [1+8192, 1+16384)  : W -> bf16
__global__ __launch_bounds__(256) void k_prep(const float* __restrict__ x,
                                              const float* __restrict__ W,
                                              const float* __restrict__ A,
                                              const float* __restrict__ Bm,
                                              __bf16* __restrict__ Xb,
                                              __bf16* __restrict__ Wb,
                                              float* __restrict__ U,
                                              float* __restrict__ G) {
  int bid = blockIdx.x;
  int t = threadIdx.x;
  int lane = t & 63, wid = t >> 6;

  if (bid == 0) {
    float g[64];
#pragma unroll
    for (int i = 0; i < 64; ++i) g[i] = 0.f;
    for (int d = t; d < DD; d += 256) {
      float br[8];
#pragma unroll
      for (int r = 0; r < 8; ++r) br[r] = Bm[r * DD + d];
#pragma unroll
      for (int r = 0; r < 8; ++r)
#pragma unroll
        for (int s = 0; s < 8; ++s) g[r * 8 + s] += br[r] * br[s];
    }
    __shared__ float gs[4][64];
#pragma unroll
    for (int i = 0; i < 64; ++i) {
      float v = g[i];
      for (int off = 32; off >= 1; off >>= 1) v += __shfl_down(v, off, 64);
      if (lane == 0) gs[wid][i] = v;
    }
    __syncthreads();
    if (t < 64) G[t] = gs[0][t] + gs[1][t] + gs[2][t] + gs[3][t];
  } else if (bid <= 8192) {
    int row = bid - 1;
    const float* xr = x + (size_t)row * DD;
    __bf16* xbr = Xb + (size_t)row * DD;
    float nsq = 0.f;
    float p[8] = {0, 0, 0, 0, 0, 0, 0, 0};
#pragma unroll
    for (int i = 0; i < 16; ++i) {
      int d = t + 256 * i;
      float xv = xr[d];
      xbr[d] = f2bf(xv);
      nsq += xv * xv;
      f32x4 a0 = *reinterpret_cast<const f32x4*>(A + (size_t)d * 8);
      f32x4 a1 = *reinterpret_cast<const f32x4*>(A + (size_t)d * 8 + 4);
      p[0] += xv * a0[0]; p[1] += xv * a0[1]; p[2] += xv * a0[2]; p[3] += xv * a0[3];
      p[4] += xv * a1[0]; p[5] += xv * a1[1]; p[6] += xv * a1[2]; p[7] += xv * a1[3];
    }
    for (int off = 32; off >= 1; off >>= 1) {
      nsq += __shfl_down(nsq, off, 64);
#pragma unroll
      for (int r = 0; r < 8; ++r) p[r] += __shfl_down(p[r], off, 64);
    }
    __shared__ float red[4][9];
    if (lane == 0) {
      red[wid][0] = nsq;
#pragma unroll
      for (int r = 0; r < 8; ++r) red[wid][1 + r] = p[r];
    }
    __syncthreads();
    if (t == 0) {
      float ns = red[0][0] + red[1][0] + red[2][0] + red[3][0];
      float u[8];
#pragma unroll
      for (int r = 0; r < 8; ++r)
        u[r] = red[0][1 + r] + red[1][1 + r] + red[2][1 + r] + red[3][1 + r];
      float n = sqrtf(ns);
      float s1 = fminf(n, 1.5f) / fmaxf(n, 1e-7f);
#pragma unroll
      for (int r = 0; r < 8; ++r) U[(size_t)row * 8 + r] = s1 * u[r];
    }
  } else {
    int i = (bid - 8193) * 256 + t;
    const f32x4* s = reinterpret_cast<const f32x4*>(W) + (size_t)i * 2;
    f32x4 v0 = s[0], v1 = s[1];
    bf16x8 o;
    o[0] = f2bf(v0[0]); o[1] = f2bf(v0[1]); o[2] = f2bf(v0[2]); o[3] = f2bf(v0[3]);
    o[4] = f2bf(v1[0]); o[5] = f2bf(v1[1]); o[6] = f2bf(v1[2]); o[7] = f2bf(v1[3]);
    reinterpret_cast<bf16x8*>(Wb)[i] = o;
  }
}

// ---------------- main GEMM: out = Xb@Wb^T + bias + c @ B ----------------
// LDS: 2 buffers x 32KB: buf b = { B[256][32] @ b*32768, A[256][32] @ +16384 },
// rows 64B, slot-swizzled phys_slot = logical_slot ^ ((row>>1)&3) (verified
// round 5: conflicts 2.4e6, free). Source k-offset inverse-swizzles:
// j = (t&3)^((t>>3)&3). Per K32-tile, 2 phases:
//  P1: LDA(m0-3)+LDB; STAGE(next.B -> buf^1); BAR; lgkm0; MFMA m0-3; BAR;
//  P2: LDA(m4-7);     STAGE(next.A -> buf^1); BAR; lgkm0; MFMA m4-7;
//      vmcnt(0); BAR;   // next tile reads buf^1 -> must be landed
// The vmcnt(0) drain is hidden by the co-resident second block per CU.
__global__ __launch_bounds__(512, 4) void k_gemm(const __bf16* __restrict__ Xb,
                                                 const __bf16* __restrict__ Wb,
                                                 const float* __restrict__ bias,
                                                 const float* __restrict__ U,
                                                 const float* __restrict__ G,
                                                 const float* __restrict__ Bm,
                                                 float* __restrict__ out) {
  __shared__ union {
    char raw[65536];
    struct { float cs[256][8]; float bs2[8][256]; } epi;
  } sm;
  char* smc = sm.raw;

  const int nwg = (MR / BM) * (DD / BN);  // 512, %8==0 -> bijective swizzle
  int wg = ((int)blockIdx.x % 8) * (nwg / 8) + (int)blockIdx.x / 8;
  int tm = wg / (DD / BN);
  int tn = wg % (DD / BN);
  int row0 = tm * BM, col0 = tn * BN;

  int t = threadIdx.x;
  int lane = t & 63, wid = t >> 6;
  int wm = wid >> 2, wn = wid & 3;  // 2x4 waves, each owns 128x64 of C
  int fr = lane & 15;
  int hi = lane >> 4;
  int sw = (fr >> 1) & 3;  // read-side swizzle key

  f32x4 acc[8][4] = {};
  bf16x8 aF[4], bF[4];

  // stage one 16KB region (K32-tile tau) -> ldsOff; 2 loads/thread.
  auto STAGE = [&](const __bf16* mat, int rowbase, int tau, int ldsOff) {
    int j = (t & 3) ^ ((t >> 3) & 3);
    int kk = (tau << 5) + (j << 3);
    const __bf16* src = mat + (size_t)(rowbase + (t >> 2)) * DD + kk;
    char* dst = smc + ldsOff + t * 16;
    GLOAD_LDS16(src, dst);
    GLOAD_LDS16(src + (size_t)128 * DD, dst + 8192);
  };

#define LDA(buf, mbase)                                                         \
  _Pragma("unroll") for (int j = 0; j < 4; ++j) aF[j] =                         \
      *reinterpret_cast<const bf16x8*>(smc + (buf)*32768 + 16384 +              \
                                       (wm * 128 + ((mbase) + j) * 16 + fr) * 64 + \
                                       ((hi ^ sw) << 4));
#define LDB(buf)                                                                \
  _Pragma("unroll") for (int j = 0; j < 4; ++j) bF[j] =                         \
      *reinterpret_cast<const bf16x8*>(smc + (buf)*32768 +                      \
                                       (wn * 64 + j * 16 + fr) * 64 +           \
                                       ((hi ^ sw) << 4));
#define MMQ(mbase)                                                              \
  __builtin_amdgcn_s_setprio(1);                                                \
  _Pragma("unroll") for (int j = 0; j < 4; ++j)                                 \
      _Pragma("unroll") for (int n = 0; n < 4; ++n)                             \
          acc[(mbase) + j][n] = __builtin_amdgcn_mfma_f32_16x16x32_bf16(        \
              aF[j], bF[n], acc[(mbase) + j][n], 0, 0, 0);                      \
  __builtin_amdgcn_s_setprio(0);
#define BAR() __builtin_amdgcn_s_barrier()
#define LGKM0() asm volatile("s_waitcnt lgkmcnt(0)" ::: "memory")
#define VM0() asm volatile("s_waitcnt vmcnt(0)" ::: "memory")

  // -------- prologue: tile 0 into buf0 --------
  STAGE(Wb, col0, 0, 0);
  STAGE(Xb, row0, 0, 16384);
  VM0();
  BAR();

  // -------- main loop: 128 K32-tiles, manual 2x unroll for static buf --------
  for (int ii = 0; ii < 64; ++ii) {
    int T = 2 * ii;
    // ---- tile T (buf0), stage tile T+1 -> buf1 ----
    LDA(0, 0); LDB(0);
    STAGE(Wb, col0, T + 1, 32768);
    BAR(); LGKM0();
    MMQ(0);
    BAR();
    LDA(0, 4);
    STAGE(Xb, row0, T + 1, 32768 + 16384);
    BAR(); LGKM0();
    MMQ(4);
    VM0();
    BAR();
    // ---- tile T+1 (buf1), stage tile T+2 -> buf0 (guard last) ----
    LDA(1, 0); LDB(1);
    if (ii < 63) STAGE(Wb, col0, T + 2, 0);
    BAR(); LGKM0();
    MMQ(0);
    BAR();
    LDA(1, 4);
    if (ii < 63) STAGE(Xb, row0, T + 2, 16384);
    BAR(); LGKM0();
    MMQ(4);
    VM0();
    BAR();
  }

  // -------- epilogue: compute c from U,G; stage B slice; write out --------
  __syncthreads();
  {
    int rr = t >> 6, cc = (t & 63) * 4;
    *reinterpret_cast<f32x4*>(&sm.epi.bs2[rr][cc]) =
        *reinterpret_cast<const f32x4*>(Bm + (size_t)rr * DD + col0 + cc);
  }
  if (t < 256) {
    f32x4 u0 = *reinterpret_cast<const f32x4*>(U + (size_t)(row0 + t) * 8);
    f32x4 u1 = *reinterpret_cast<const f32x4*>(U + (size_t)(row0 + t) * 8 + 4);
    float u[8] = {u0[0], u0[1], u0[2], u0[3], u1[0], u1[1], u1[2], u1[3]};
    float n2sq = 0.f;
#pragma unroll
    for (int r = 0; r < 8; ++r) {
      float s = 0.f;
#pragma unroll
      for (int q = 0; q < 8; ++q) s += G[r * 8 + q] * u[q];
      n2sq += u[r] * s;
    }
    float n2 = sqrtf(fmaxf(n2sq, 0.f));
    float sc2 = 2.0f * fminf(n2, 1.5f) / fmaxf(n2, 1e-7f);
#pragma unroll
    for (int r = 0; r < 8; ++r) sm.epi.cs[t][r] = sc2 * u[r];
  }
  __syncthreads();

  int colb = col0 + wn * 64 + fr;
  float biasv[4], bcol[4][8];
#pragma unroll
  for (int n = 0; n < 4; ++n) {
    biasv[n] = bias[colb + n * 16];
#pragma unroll
    for (int r = 0; r < 8; ++r) bcol[n][r] = sm.epi.bs2[r][wn * 64 + fr + n * 16];
  }
#pragma unroll
  for (int m = 0; m < 8; ++m) {
#pragma unroll
    for (int j = 0; j < 4; ++j) {
      int rl = wm * 128 + m * 16 + hi * 4 + j;
      float c0 = sm.epi.cs[rl][0], c1 = sm.epi.cs[rl][1], c2 = sm.epi.cs[rl][2],
            c3 = sm.epi.cs[rl][3], c4 = sm.epi.cs[rl][4], c5 = sm.epi.cs[rl][5],
            c6 = sm.epi.cs[rl][6], c7 = sm.epi.cs[rl][7];
      float* orow = out + (size_t)(row0 + rl) * DD + colb;
#pragma unroll
      for (int n = 0; n < 4; ++n) {
        float delta = c0 * bcol[n][0] + c1 * bcol[n][1] + c2 * bcol[n][2] +
                      c3 * bcol[n][3] + c4 * bcol[n][4] + c5 * bcol[n][5] +
                      c6 * bcol[n][6] + c7 * bcol[n][7];
        orow[n * 16] = acc[m][n][j] + biasv[n] + delta;
      }
    }
  }
}

extern "C" void kernel_launch(void* const* d_in, const int* in_sizes, int n_in,
                              void* d_out, int out_size, void* d_ws, size_t ws_size,
                              hipStream_t stream) {
  const float* x = (const float*)d_in[0];   // [4,2048,4096]
  const float* W = (const float*)d_in[1];   // [4096,4096]
  const float* b = (const float*)d_in[2];   // [4096]
  const float* A = (const float*)d_in[3];   // [4096,8]
  const float* Bm = (const float*)d_in[4];  // [8,4096]
  // d_in[5] = log_K : K cancels analytically, unused.
  float* out = (float*)d_out;

  char* ws = (char*)d_ws;
  __bf16* Xb = (__bf16*)ws;                                    // 64 MB
  __bf16* Wb = (__bf16*)(ws + (size_t)64 * 1024 * 1024);       // 32 MB
  float* U = (float*)(ws + (size_t)96 * 1024 * 1024);          // 256 KB
  float* G = (float*)(ws + (size_t)96 * 1024 * 1024 + 256 * 1024);

  k_prep<<<1 + 8192 + 8192, 256, 0, stream>>>(x, W, A, Bm, Xb, Wb, U, G);
  k_gemm<<<(MR / BM) * (DD / BN), 512, 0, stream>>>(Xb, Wb, b, U, G, Bm, out);
}

// Round 8
// 419.754 us; speedup vs baseline: 6.3673x; 6.3673x over previous
//
#include <hip/hip_runtime.h>
#include <hip/hip_bf16.h>

// HypLoRA: out = x@W^T + b + 2 * scale2(row) * (u(row) @ B)
//   u(row)    = s1 * (x_row @ A), s1 = min(||x||,1.5)/max(||x||,EPS)
//   scale2    = min(n2,1.5)/max(n2,EPS),  n2^2 = u^T (B B^T) u
// K = clip(exp(log_K),...) cancels identically in log(exp(.)) at origin.
//
// Launch 1 (k_prep): G = B B^T | per-row u = s1*(x@A) + x->bf16 | W->bf16
// Launch 2 (k_gemm): round-5 champion structure (256x256, BK=64, 8-phase,
// 2x64KB LDS dbuf, slot swizzle) + address hoisting: incrementing global
// pointers for STAGE, immediate-offset ds_reads off 4 precomputed bases.
// NOTE round-7 lesson: launch_bounds(512,4) caps VGPR at 128 -> acc spills
// to scratch (7.5GB writes). 256^2 tile requires (512,2). Do not revisit.

#define DD 4096
#define MR 8192
#define BM 256
#define BN 256

typedef float f32x4 __attribute__((ext_vector_type(4)));
typedef __bf16 bf16x8 __attribute__((ext_vector_type(8)));
typedef __bf16 bf16x4 __attribute__((ext_vector_type(4)));

#define GLOAD_LDS16(gptr, lptr)                                                        \
  __builtin_amdgcn_global_load_lds((const __attribute__((address_space(1))) void*)(gptr), \
                                   (__attribute__((address_space(3))) void*)(lptr), 16, 0, 0)

__device__ __forceinline__ __bf16 f2bf(float f) { return (__bf16)f; }

// ---------------- fused prep ----------------
// bid 0                  : G = B B^T (8x8)
// bid [1, 1+8192)        : row r: u[r] = s1 * (x_r @ A); Xb = bf16(x)
// bid [1+8192, 1+16384)  : W -> bf16
__global__ __launch_bounds__(256) void k_prep(const float* __restrict__ x,
                                              const float* __restrict__ W,
                                              const float* __restrict__ A,
                                              const float* __restrict__ Bm,
                                              __bf16* __restrict__ Xb,
                                              __bf16* __restrict__ Wb,
                                              float* __restrict__ U,
                                              float* __restrict__ G) {
  int bid = blockIdx.x;
  int t = threadIdx.x;
  int lane = t & 63, wid = t >> 6;

  if (bid == 0) {
    float g[64];
#pragma unroll
    for (int i = 0; i < 64; ++i) g[i] = 0.f;
    for (int d = t; d < DD; d += 256) {
      float br[8];
#pragma unroll
      for (int r = 0; r < 8; ++r) br[r] = Bm[r * DD + d];
#pragma unroll
      for (int r = 0; r < 8; ++r)
#pragma unroll
        for (int s = 0; s < 8; ++s) g[r * 8 + s] += br[r] * br[s];
    }
    __shared__ float gs[4][64];
#pragma unroll
    for (int i = 0; i < 64; ++i) {
      float v = g[i];
      for (int off = 32; off >= 1; off >>= 1) v += __shfl_down(v, off, 64);
      if (lane == 0) gs[wid][i] = v;
    }
    __syncthreads();
    if (t < 64) G[t] = gs[0][t] + gs[1][t] + gs[2][t] + gs[3][t];
  } else if (bid <= 8192) {
    // per-row u + x->bf16. f32x4 loads / bf16x4 stores; lane-consecutive 16B
    // chunks keep the wave's x-access contiguous; A-lines (stride-128B gather)
    // are reused across the inner j=0..3 in L1.
    int row = bid - 1;
    const float* xr = x + (size_t)row * DD;
    __bf16* xbr = Xb + (size_t)row * DD;
    float nsq = 0.f;
    float p[8] = {0, 0, 0, 0, 0, 0, 0, 0};
    int base = t * 4;
#pragma unroll
    for (int i = 0; i < 4; ++i) {
      int d0 = base + 1024 * i;
      f32x4 xv = *reinterpret_cast<const f32x4*>(xr + d0);
      bf16x4 o;
#pragma unroll
      for (int j = 0; j < 4; ++j) {
        float x1 = xv[j];
        o[j] = f2bf(x1);
        nsq += x1 * x1;
        f32x4 a0 = *reinterpret_cast<const f32x4*>(A + (size_t)(d0 + j) * 8);
        f32x4 a1 = *reinterpret_cast<const f32x4*>(A + (size_t)(d0 + j) * 8 + 4);
        p[0] += x1 * a0[0]; p[1] += x1 * a0[1]; p[2] += x1 * a0[2]; p[3] += x1 * a0[3];
        p[4] += x1 * a1[0]; p[5] += x1 * a1[1]; p[6] += x1 * a1[2]; p[7] += x1 * a1[3];
      }
      *reinterpret_cast<bf16x4*>(xbr + d0) = o;
    }
    for (int off = 32; off >= 1; off >>= 1) {
      nsq += __shfl_down(nsq, off, 64);
#pragma unroll
      for (int r = 0; r < 8; ++r) p[r] += __shfl_down(p[r], off, 64);
    }
    __shared__ float red[4][9];
    if (lane == 0) {
      red[wid][0] = nsq;
#pragma unroll
      for (int r = 0; r < 8; ++r) red[wid][1 + r] = p[r];
    }
    __syncthreads();
    if (t == 0) {
      float ns = red[0][0] + red[1][0] + red[2][0] + red[3][0];
      float u[8];
#pragma unroll
      for (int r = 0; r < 8; ++r)
        u[r] = red[0][1 + r] + red[1][1 + r] + red[2][1 + r] + red[3][1 + r];
      float n = sqrtf(ns);
      float s1 = fminf(n, 1.5f) / fmaxf(n, 1e-7f);
#pragma unroll
      for (int r = 0; r < 8; ++r) U[(size_t)row * 8 + r] = s1 * u[r];
    }
  } else {
    int i = (bid - 8193) * 256 + t;
    const f32x4* s = reinterpret_cast<const f32x4*>(W) + (size_t)i * 2;
    f32x4 v0 = s[0], v1 = s[1];
    bf16x8 o;
    o[0] = f2bf(v0[0]); o[1] = f2bf(v0[1]); o[2] = f2bf(v0[2]); o[3] = f2bf(v0[3]);
    o[4] = f2bf(v1[0]); o[5] = f2bf(v1[1]); o[6] = f2bf(v1[2]); o[7] = f2bf(v1[3]);
    reinterpret_cast<bf16x8*>(Wb)[i] = o;
  }
}

// ---------------- main GEMM: out = Xb@Wb^T + bias + c @ B ----------------
// LDS per buffer (64KB): [0,16K)=B.k0, [16K,32K)=A.k0, [32K,48K)=B.k1,
// [48K,64K)=A.k1; regions [256][32] bf16 (64B rows), slot swizzle
// phys_slot = logical_slot ^ ((row>>1)&3); source k-offset inverse-swizzled
// j = (t&3)^((t>>3)&3). Global staging via 4 incrementing pointers (+32 elems
// per stage); LDS fragment reads are ds_read_b128 with compile-time offsets
// (ks*32768 + m*1024 <= 39936) off 4 precomputed per-thread bases -> no
// per-phase address VALU. vmcnt(6) at P4/P8 (P4 -> vmcnt(0) on last iter,
// where P2-P8 stages are skipped and the retire-count argument breaks).
__global__ __launch_bounds__(512, 2) void k_gemm(const __bf16* __restrict__ Xb,
                                                 const __bf16* __restrict__ Wb,
                                                 const float* __restrict__ bias,
                                                 const float* __restrict__ U,
                                                 const float* __restrict__ G,
                                                 const float* __restrict__ Bm,
                                                 float* __restrict__ out) {
  __shared__ union {
    char raw[131072];
    struct { float cs[256][8]; float bs2[8][256]; } epi;
  } sm;
  char* smc = sm.raw;

  const int nwg = (MR / BM) * (DD / BN);  // 512, %8==0 -> bijective swizzle
  int wg = ((int)blockIdx.x % 8) * (nwg / 8) + (int)blockIdx.x / 8;
  int tm = wg / (DD / BN);
  int tn = wg % (DD / BN);
  int row0 = tm * BM, col0 = tn * BN;

  int t = threadIdx.x;
  int lane = t & 63, wid = t >> 6;
  int wm = wid >> 2, wn = wid & 3;  // 2x4 waves, each owns 128x64 of C
  int fr = lane & 15;
  int hi = lane >> 4;
  int sw = (fr >> 1) & 3;

  f32x4 acc[8][4] = {};
  bf16x8 aF[4], bF[4];

  // ---- hoisted addressing ----
  int jsw = (t & 3) ^ ((t >> 3) & 3);
  const __bf16* sW = Wb + (size_t)(col0 + (t >> 2)) * DD + jsw * 8;
  const __bf16* sW2 = sW + (size_t)128 * DD;
  const __bf16* sX = Xb + (size_t)(row0 + (t >> 2)) * DD + jsw * 8;
  const __bf16* sX2 = sX + (size_t)128 * DD;
  char* dT = smc + t * 16;

  auto SW = [&](int off) {
    GLOAD_LDS16(sW, dT + off);
    GLOAD_LDS16(sW2, dT + off + 8192);
    sW += 32; sW2 += 32;
  };
  auto SX = [&](int off) {
    GLOAD_LDS16(sX, dT + off);
    GLOAD_LDS16(sX2, dT + off + 8192);
    sX += 32; sX2 += 32;
  };

  const char* aB0 = smc + 16384 + (wm * 128 + fr) * 64 + ((hi ^ sw) << 4);
  const char* aB1 = aB0 + 65536;
  const char* bB0 = smc + (wn * 64 + fr) * 64 + ((hi ^ sw) << 4);
  const char* bB1 = bB0 + 65536;

#define LDA(base, ks, mbase)                                                    \
  _Pragma("unroll") for (int j = 0; j < 4; ++j) aF[j] =                         \
      *reinterpret_cast<const bf16x8*>((base) + (ks)*32768 + ((mbase) + j) * 1024);
#define LDB(base, ks)                                                           \
  _Pragma("unroll") for (int j = 0; j < 4; ++j) bF[j] =                         \
      *reinterpret_cast<const bf16x8*>((base) + (ks)*32768 + j * 1024);
#define MMQ(mbase)                                                              \
  __builtin_amdgcn_s_setprio(1);                                                \
  _Pragma("unroll") for (int j = 0; j < 4; ++j)                                 \
      _Pragma("unroll") for (int n = 0; n < 4; ++n)                             \
          acc[(mbase) + j][n] = __builtin_amdgcn_mfma_f32_16x16x32_bf16(        \
              aF[j], bF[n], acc[(mbase) + j][n], 0, 0, 0);                      \
  __builtin_amdgcn_s_setprio(0);
#define BAR() __builtin_amdgcn_s_barrier()
#define LGKM0() asm volatile("s_waitcnt lgkmcnt(0)" ::: "memory")

  // -------- prologue: tile0 all 4 regions, tile1 first 3 --------
  SW(0); SX(16384); SW(32768); SX(49152);
  asm volatile("s_waitcnt vmcnt(4)" ::: "memory");
  SW(65536); SX(81920); SW(98304);
  asm volatile("s_waitcnt vmcnt(6)" ::: "memory");  // tile0 fully landed
  BAR();

  for (int i = 0; i < 32; ++i) {
    bool nt = (i < 31);
    // P1: tile 2i, ks0, m0-3 ; stage X(2i+1, ks1) -> buf1.Ak1
    LDA(aB0, 0, 0); LDB(bB0, 0);
    SX(114688);
    BAR(); LGKM0();
    MMQ(0);
    BAR();
    // P2: ks0, m4-7 ; stage W(2i+2, ks0) -> buf0.Bk0
    LDA(aB0, 0, 4);
    if (nt) SW(0);
    BAR(); LGKM0();
    MMQ(4);
    BAR();
    // P3: ks1, m0-3 ; stage X(2i+2, ks0) -> buf0.Ak0
    LDA(aB0, 1, 0); LDB(bB0, 1);
    if (nt) SX(16384);
    BAR(); LGKM0();
    MMQ(0);
    BAR();
    // P4: ks1, m4-7 ; stage W(2i+2, ks1) -> buf0.Bk1 ; wait tile 2i+1
    LDA(aB0, 1, 4);
    if (nt) SW(32768);
    BAR(); LGKM0();
    MMQ(4);
    if (nt) { asm volatile("s_waitcnt vmcnt(6)" ::: "memory"); }
    else    { asm volatile("s_waitcnt vmcnt(0)" ::: "memory"); }
    BAR();
    // P5: tile 2i+1, ks0, m0-3 ; stage X(2i+2, ks1) -> buf0.Ak1
    LDA(aB1, 0, 0); LDB(bB1, 0);
    if (nt) SX(49152);
    BAR(); LGKM0();
    MMQ(0);
    BAR();
    // P6: ks0, m4-7 ; stage W(2i+3, ks0) -> buf1.Bk0
    LDA(aB1, 0, 4);
    if (nt) SW(65536);
    BAR(); LGKM0();
    MMQ(4);
    BAR();
    // P7: ks1, m0-3 ; stage X(2i+3, ks0) -> buf1.Ak0
    LDA(aB1, 1, 0); LDB(bB1, 1);
    if (nt) SX(81920);
    BAR(); LGKM0();
    MMQ(0);
    BAR();
    // P8: ks1, m4-7 ; stage W(2i+3, ks1) -> buf1.Bk1 ; wait tile 2i+2
    LDA(aB1, 1, 4);
    if (nt) SW(98304);
    BAR(); LGKM0();
    MMQ(4);
    asm volatile("s_waitcnt vmcnt(6)" ::: "memory");  // no-op on last iter
    BAR();
  }

  // -------- epilogue: drain DMA, compute c from U,G; stage B slice --------
  asm volatile("s_waitcnt vmcnt(0)" ::: "memory");
  __syncthreads();
  {
    int rr = t >> 6, cc = (t & 63) * 4;
    *reinterpret_cast<f32x4*>(&sm.epi.bs2[rr][cc]) =
        *reinterpret_cast<const f32x4*>(Bm + (size_t)rr * DD + col0 + cc);
  }
  if (t < 256) {
    f32x4 u0 = *reinterpret_cast<const f32x4*>(U + (size_t)(row0 + t) * 8);
    f32x4 u1 = *reinterpret_cast<const f32x4*>(U + (size_t)(row0 + t) * 8 + 4);
    float u[8] = {u0[0], u0[1], u0[2], u0[3], u1[0], u1[1], u1[2], u1[3]};
    float n2sq = 0.f;
#pragma unroll
    for (int r = 0; r < 8; ++r) {
      float s = 0.f;
#pragma unroll
      for (int q = 0; q < 8; ++q) s += G[r * 8 + q] * u[q];
      n2sq += u[r] * s;
    }
    float n2 = sqrtf(fmaxf(n2sq, 0.f));
    float sc2 = 2.0f * fminf(n2, 1.5f) / fmaxf(n2, 1e-7f);
#pragma unroll
    for (int r = 0; r < 8; ++r) sm.epi.cs[t][r] = sc2 * u[r];
  }
  __syncthreads();

  int colb = col0 + wn * 64 + fr;
  float biasv[4], bcol[4][8];
#pragma unroll
  for (int n = 0; n < 4; ++n) {
    biasv[n] = bias[colb + n * 16];
#pragma unroll
    for (int r = 0; r < 8; ++r) bcol[n][r] = sm.epi.bs2[r][wn * 64 + fr + n * 16];
  }
#pragma unroll
  for (int m = 0; m < 8; ++m) {
#pragma unroll
    for (int j = 0; j < 4; ++j) {
      int rl = wm * 128 + m * 16 + hi * 4 + j;
      float c0 = sm.epi.cs[rl][0], c1 = sm.epi.cs[rl][1], c2 = sm.epi.cs[rl][2],
            c3 = sm.epi.cs[rl][3], c4 = sm.epi.cs[rl][4], c5 = sm.epi.cs[rl][5],
            c6 = sm.epi.cs[rl][6], c7 = sm.epi.cs[rl][7];
      float* orow = out + (size_t)(row0 + rl) * DD + colb;
#pragma unroll
      for (int n = 0; n < 4; ++n) {
        float delta = c0 * bcol[n][0] + c1 * bcol[n][1] + c2 * bcol[n][2] +
                      c3 * bcol[n][3] + c4 * bcol[n][4] + c5 * bcol[n][5] +
                      c6 * bcol[n][6] + c7 * bcol[n][7];
        orow[n * 16] = acc[m][n][j] + biasv[n] + delta;
      }
    }
  }
}

extern "C" void kernel_launch(void* const* d_in, const int* in_sizes, int n_in,
                              void* d_out, int out_size, void* d_ws, size_t ws_size,
                              hipStream_t stream) {
  const float* x = (const float*)d_in[0];   // [4,2048,4096]
  const float* W = (const float*)d_in[1];   // [4096,4096]
  const float* b = (const float*)d_in[2];   // [4096]
  const float* A = (const float*)d_in[3];   // [4096,8]
  const float* Bm = (const float*)d_in[4];  // [8,4096]
  // d_in[5] = log_K : K cancels analytically, unused.
  float* out = (float*)d_out;

  char* ws = (char*)d_ws;
  __bf16* Xb = (__bf16*)ws;                                    // 64 MB
  __bf16* Wb = (__bf16*)(ws + (size_t)64 * 1024 * 1024);       // 32 MB
  float* U = (float*)(ws + (size_t)96 * 1024 * 1024);          // 256 KB
  float* G = (float*)(ws + (size_t)96 * 1024 * 1024 + 256 * 1024);

  k_prep<<<1 + 8192 + 8192, 256, 0, stream>>>(x, W, A, Bm, Xb, Wb, U, G);
  k_gemm<<<(MR / BM) * (DD / BN), 512, 0, stream>>>(Xb, Wb, b, U, G, Bm, out);
}

// Round 9
// 359.400 us; speedup vs baseline: 7.4366x; 1.1679x over previous
//
#include <hip/hip_runtime.h>
#include <hip/hip_bf16.h>

// HypLoRA: out = x@W^T + b + 2 * scale2(row) * (u(row) @ B)
//   u(row)    = s1 * (x_row @ A), s1 = min(||x||,1.5)/max(||x||,EPS)
//   scale2    = min(n2,1.5)/max(n2,EPS),  n2^2 = u^T (B B^T) u
// K = clip(exp(log_K),...) cancels identically in log(exp(.)) at origin.
//
// Launch 1 (k_prep): round-5 proven version (scalar coalesced k_rows).
// Launch 2 (k_gemm): round-6 pipelined 8-phase schedule + sched_group_barrier
// pins (DS_READ before MFMA) to force cross-pipe overlap the compiler didn't
// produce on its own (round-6 was neutral; hypothesis: reads got interleaved
// after MFMAs).
// Round-7 lesson: launch_bounds(512,4) caps VGPR at 128 -> acc spills (7.5GB
// scratch traffic). 256^2 tile requires (512,2). Do not revisit.
// Round-8 lesson: VALU addr work is not on the critical path; k_rows must
// keep lane-consecutive d (coalesced A rows).

#define DD 4096
#define MR 8192
#define BM 256
#define BN 256
#define BK 64

typedef float f32x4 __attribute__((ext_vector_type(4)));
typedef __bf16 bf16x8 __attribute__((ext_vector_type(8)));

#define GLOAD_LDS16(gptr, lptr)                                                        \
  __builtin_amdgcn_global_load_lds((const __attribute__((address_space(1))) void*)(gptr), \
                                   (__attribute__((address_space(3))) void*)(lptr), 16, 0, 0)

__device__ __forceinline__ __bf16 f2bf(float f) { return (__bf16)f; }

// ---------------- fused prep (round-5 proven) ----------------
// bid 0                  : G = B B^T (8x8)
// bid [1, 1+8192)        : row r: u[r] = s1 * (x_r @ A); Xb = bf16(x)
// bid [1+8192, 1+16384)  : W -> bf16
__global__ __launch_bounds__(256) void k_prep(const float* __restrict__ x,
                                              const float* __restrict__ W,
                                              const float* __restrict__ A,
                                              const float* __restrict__ Bm,
                                              __bf16* __restrict__ Xb,
                                              __bf16* __restrict__ Wb,
                                              float* __restrict__ U,
                                              float* __restrict__ G) {
  int bid = blockIdx.x;
  int t = threadIdx.x;
  int lane = t & 63, wid = t >> 6;

  if (bid == 0) {
    float g[64];
#pragma unroll
    for (int i = 0; i < 64; ++i) g[i] = 0.f;
    for (int d = t; d < DD; d += 256) {
      float br[8];
#pragma unroll
      for (int r = 0; r < 8; ++r) br[r] = Bm[r * DD + d];
#pragma unroll
      for (int r = 0; r < 8; ++r)
#pragma unroll
        for (int s = 0; s < 8; ++s) g[r * 8 + s] += br[r] * br[s];
    }
    __shared__ float gs[4][64];
#pragma unroll
    for (int i = 0; i < 64; ++i) {
      float v = g[i];
      for (int off = 32; off >= 1; off >>= 1) v += __shfl_down(v, off, 64);
      if (lane == 0) gs[wid][i] = v;
    }
    __syncthreads();
    if (t < 64) G[t] = gs[0][t] + gs[1][t] + gs[2][t] + gs[3][t];
  } else if (bid <= 8192) {
    int row = bid - 1;
    const float* xr = x + (size_t)row * DD;
    __bf16* xbr = Xb + (size_t)row * DD;
    float nsq = 0.f;
    float p[8] = {0, 0, 0, 0, 0, 0, 0, 0};
#pragma unroll
    for (int i = 0; i < 16; ++i) {
      int d = t + 256 * i;
      float xv = xr[d];
      xbr[d] = f2bf(xv);
      nsq += xv * xv;
      f32x4 a0 = *reinterpret_cast<const f32x4*>(A + (size_t)d * 8);
      f32x4 a1 = *reinterpret_cast<const f32x4*>(A + (size_t)d * 8 + 4);
      p[0] += xv * a0[0]; p[1] += xv * a0[1]; p[2] += xv * a0[2]; p[3] += xv * a0[3];
      p[4] += xv * a1[0]; p[5] += xv * a1[1]; p[6] += xv * a1[2]; p[7] += xv * a1[3];
    }
    for (int off = 32; off >= 1; off >>= 1) {
      nsq += __shfl_down(nsq, off, 64);
#pragma unroll
      for (int r = 0; r < 8; ++r) p[r] += __shfl_down(p[r], off, 64);
    }
    __shared__ float red[4][9];
    if (lane == 0) {
      red[wid][0] = nsq;
#pragma unroll
      for (int r = 0; r < 8; ++r) red[wid][1 + r] = p[r];
    }
    __syncthreads();
    if (t == 0) {
      float ns = red[0][0] + red[1][0] + red[2][0] + red[3][0];
      float u[8];
#pragma unroll
      for (int r = 0; r < 8; ++r)
        u[r] = red[0][1 + r] + red[1][1 + r] + red[2][1 + r] + red[3][1 + r];
      float n = sqrtf(ns);
      float s1 = fminf(n, 1.5f) / fmaxf(n, 1e-7f);
#pragma unroll
      for (int r = 0; r < 8; ++r) U[(size_t)row * 8 + r] = s1 * u[r];
    }
  } else {
    int i = (bid - 8193) * 256 + t;
    const f32x4* s = reinterpret_cast<const f32x4*>(W) + (size_t)i * 2;
    f32x4 v0 = s[0], v1 = s[1];
    bf16x8 o;
    o[0] = f2bf(v0[0]); o[1] = f2bf(v0[1]); o[2] = f2bf(v0[2]); o[3] = f2bf(v0[3]);
    o[4] = f2bf(v1[0]); o[5] = f2bf(v1[1]); o[6] = f2bf(v1[2]); o[7] = f2bf(v1[3]);
    reinterpret_cast<bf16x8*>(Wb)[i] = o;
  }
}

// ---------------- main GEMM: out = Xb@Wb^T + bias + c @ B ----------------
// LDS per buffer (64KB): [0,16K)=B.k0, [16K,32K)=A.k0, [32K,48K)=B.k1,
// [48K,64K)=A.k1; regions [256][32] bf16, slot swizzle phys_slot =
// logical_slot ^ ((row>>1)&3); source k-offset inverse-swizzled
// j = (t&3)^((t>>3)&3). Fragment reads for phase k+1 issue inside phase k
// (aA/aB, bA/bB double-buffers, round-6 schedule, correctness-verified) and
// are PINNED before the MFMA cluster by sched_group_barrier so they drain
// while the MFMAs execute. vmcnt(6) at P4/P8 after BAR; STAGE taus wrap &63
// on the tail (dead-but-safe loads keep the vmcnt retire-count argument).
__global__ __launch_bounds__(512, 2) void k_gemm(const __bf16* __restrict__ Xb,
                                                 const __bf16* __restrict__ Wb,
                                                 const float* __restrict__ bias,
                                                 const float* __restrict__ U,
                                                 const float* __restrict__ G,
                                                 const float* __restrict__ Bm,
                                                 float* __restrict__ out) {
  __shared__ union {
    char raw[131072];
    struct { float cs[256][8]; float bs2[8][256]; } epi;
  } sm;
  char* smc = sm.raw;

  const int nwg = (MR / BM) * (DD / BN);  // 512, %8==0 -> bijective swizzle
  int wg = ((int)blockIdx.x % 8) * (nwg / 8) + (int)blockIdx.x / 8;
  int tm = wg / (DD / BN);
  int tn = wg % (DD / BN);
  int row0 = tm * BM, col0 = tn * BN;

  int t = threadIdx.x;
  int lane = t & 63, wid = t >> 6;
  int wm = wid >> 2, wn = wid & 3;  // 2x4 waves, each owns 128x64 of C
  int fr = lane & 15;
  int hi = lane >> 4;
  int sw = (fr >> 1) & 3;  // read-side swizzle key

  f32x4 acc[8][4] = {};
  bf16x8 aA[4], aB[4], bA[4], bB[4];

  auto STAGE = [&](const __bf16* mat, int rowbase, int tau, int ks, int ldsOff) {
    int j = (t & 3) ^ ((t >> 3) & 3);
    int kk = ((tau & 63) << 6) + (ks << 5) + (j << 3);
    const __bf16* src = mat + (size_t)(rowbase + (t >> 2)) * DD + kk;
    char* dst = smc + ldsOff + t * 16;
    GLOAD_LDS16(src, dst);
    GLOAD_LDS16(src + (size_t)128 * DD, dst + 8192);
  };

#define LDA(dst, buf, ks, mbase)                                                \
  _Pragma("unroll") for (int j = 0; j < 4; ++j) dst[j] =                        \
      *reinterpret_cast<const bf16x8*>(smc + (buf)*65536 + 16384 + (ks)*32768 + \
                                       (wm * 128 + ((mbase) + j) * 16 + fr) * 64 + \
                                       ((hi ^ sw) << 4));
#define LDB(dst, buf, ks)                                                       \
  _Pragma("unroll") for (int j = 0; j < 4; ++j) dst[j] =                        \
      *reinterpret_cast<const bf16x8*>(smc + (buf)*65536 + (ks)*32768 +         \
                                       (wn * 64 + j * 16 + fr) * 64 +           \
                                       ((hi ^ sw) << 4));
#define MMQ(aset, bset, mbase)                                                  \
  __builtin_amdgcn_s_setprio(1);                                                \
  _Pragma("unroll") for (int j = 0; j < 4; ++j)                                 \
      _Pragma("unroll") for (int n = 0; n < 4; ++n)                             \
          acc[(mbase) + j][n] = __builtin_amdgcn_mfma_f32_16x16x32_bf16(        \
              aset[j], bset[n], acc[(mbase) + j][n], 0, 0, 0);                  \
  __builtin_amdgcn_s_setprio(0);
#define BAR() __builtin_amdgcn_s_barrier()
#define VM6() asm volatile("s_waitcnt vmcnt(6)" ::: "memory")
// Pin instruction order within the phase: n ds_reads first, then 16 MFMAs.
#define SGB_PIN(nreads)                                      \
  __builtin_amdgcn_sched_group_barrier(0x100, (nreads), 0);  \
  __builtin_amdgcn_sched_group_barrier(0x8, 16, 0)

  // -------- prologue: tile0 all 4 regions, tile1 first 3 --------
  STAGE(Wb, col0, 0, 0, 0);
  STAGE(Xb, row0, 0, 0, 16384);
  STAGE(Wb, col0, 0, 1, 32768);
  STAGE(Xb, row0, 0, 1, 49152);
  asm volatile("s_waitcnt vmcnt(4)" ::: "memory");
  STAGE(Wb, col0, 1, 0, 65536 + 0);
  STAGE(Xb, row0, 1, 0, 65536 + 16384);
  STAGE(Wb, col0, 1, 1, 65536 + 32768);
  VM6();  // tile0 fully landed
  BAR();
  // preload P1 fragments
  LDA(aA, 0, 0, 0);
  LDB(bA, 0, 0);

  for (int i = 0; i < DD / BK / 2; ++i) {
    int T = 2 * i;
    // P1: MMQ(aA,bA,0); prefetch P2.A
    STAGE(Xb, row0, T + 1, 1, 65536 + 49152);
    BAR();
    LDA(aB, 0, 0, 4);
    MMQ(aA, bA, 0);
    SGB_PIN(4);
    BAR();
    // P2: MMQ(aB,bA,4); prefetch P3.{A,B}
    STAGE(Wb, col0, T + 2, 0, 0);
    BAR();
    LDA(aA, 0, 1, 0);
    LDB(bB, 0, 1);
    MMQ(aB, bA, 4);
    SGB_PIN(8);
    BAR();
    // P3: MMQ(aA,bB,0); prefetch P4.A
    STAGE(Xb, row0, T + 2, 0, 16384);
    BAR();
    LDA(aB, 0, 1, 4);
    MMQ(aA, bB, 0);
    SGB_PIN(4);
    BAR();
    // P4: vmcnt; MMQ(aB,bB,4); prefetch P5.{A,B} (buf1 tile T+1, landed)
    STAGE(Wb, col0, T + 2, 1, 32768);
    BAR();
    VM6();
    LDA(aA, 1, 0, 0);
    LDB(bA, 1, 0);
    MMQ(aB, bB, 4);
    SGB_PIN(8);
    BAR();
    // P5: MMQ(aA,bA,0); prefetch P6.A
    STAGE(Xb, row0, T + 2, 1, 49152);
    BAR();
    LDA(aB, 1, 0, 4);
    MMQ(aA, bA, 0);
    SGB_PIN(4);
    BAR();
    // P6: MMQ(aB,bA,4); prefetch P7.{A,B}
    STAGE(Wb, col0, T + 3, 0, 65536 + 0);
    BAR();
    LDA(aA, 1, 1, 0);
    LDB(bB, 1, 1);
    MMQ(aB, bA, 4);
    SGB_PIN(8);
    BAR();
    // P7: MMQ(aA,bB,0); prefetch P8.A
    STAGE(Xb, row0, T + 3, 0, 65536 + 16384);
    BAR();
    LDA(aB, 1, 1, 4);
    MMQ(aA, bB, 0);
    SGB_PIN(4);
    BAR();
    // P8: vmcnt; MMQ(aB,bB,4); prefetch next-P1.{A,B} (buf0 tile T+2, landed)
    STAGE(Wb, col0, T + 3, 1, 65536 + 32768);
    BAR();
    VM6();
    LDA(aA, 0, 0, 0);
    LDB(bA, 0, 0);
    MMQ(aB, bB, 4);
    SGB_PIN(8);
    BAR();
  }

  // -------- epilogue: drain DMA, compute c from U,G; stage B slice --------
  asm volatile("s_waitcnt vmcnt(0)" ::: "memory");
  __syncthreads();
  {
    int rr = t >> 6, cc = (t & 63) * 4;
    *reinterpret_cast<f32x4*>(&sm.epi.bs2[rr][cc]) =
        *reinterpret_cast<const f32x4*>(Bm + (size_t)rr * DD + col0 + cc);
  }
  if (t < 256) {
    f32x4 u0 = *reinterpret_cast<const f32x4*>(U + (size_t)(row0 + t) * 8);
    f32x4 u1 = *reinterpret_cast<const f32x4*>(U + (size_t)(row0 + t) * 8 + 4);
    float u[8] = {u0[0], u0[1], u0[2], u0[3], u1[0], u1[1], u1[2], u1[3]};
    float n2sq = 0.f;
#pragma unroll
    for (int r = 0; r < 8; ++r) {
      float s = 0.f;
#pragma unroll
      for (int q = 0; q < 8; ++q) s += G[r * 8 + q] * u[q];
      n2sq += u[r] * s;
    }
    float n2 = sqrtf(fmaxf(n2sq, 0.f));
    float sc2 = 2.0f * fminf(n2, 1.5f) / fmaxf(n2, 1e-7f);
#pragma unroll
    for (int r = 0; r < 8; ++r) sm.epi.cs[t][r] = sc2 * u[r];
  }
  __syncthreads();

  int colb = col0 + wn * 64 + fr;
  float biasv[4], bcol[4][8];
#pragma unroll
  for (int n = 0; n < 4; ++n) {
    biasv[n] = bias[colb + n * 16];
#pragma unroll
    for (int r = 0; r < 8; ++r) bcol[n][r] = sm.epi.bs2[r][wn * 64 + fr + n * 16];
  }
#pragma unroll
  for (int m = 0; m < 8; ++m) {
#pragma unroll
    for (int j = 0; j < 4; ++j) {
      int rl = wm * 128 + m * 16 + hi * 4 + j;
      float c0 = sm.epi.cs[rl][0], c1 = sm.epi.cs[rl][1], c2 = sm.epi.cs[rl][2],
            c3 = sm.epi.cs[rl][3], c4 = sm.epi.cs[rl][4], c5 = sm.epi.cs[rl][5],
            c6 = sm.epi.cs[rl][6], c7 = sm.epi.cs[rl][7];
      float* orow = out + (size_t)(row0 + rl) * DD + colb;
#pragma unroll
      for (int n = 0; n < 4; ++n) {
        float delta = c0 * bcol[n][0] + c1 * bcol[n][1] + c2 * bcol[n][2] +
                      c3 * bcol[n][3] + c4 * bcol[n][4] + c5 * bcol[n][5] +
                      c6 * bcol[n][6] + c7 * bcol[n][7];
        orow[n * 16] = acc[m][n][j] + biasv[n] + delta;
      }
    }
  }
}

extern "C" void kernel_launch(void* const* d_in, const int* in_sizes, int n_in,
                              void* d_out, int out_size, void* d_ws, size_t ws_size,
                              hipStream_t stream) {
  const float* x = (const float*)d_in[0];   // [4,2048,4096]
  const float* W = (const float*)d_in[1];   // [4096,4096]
  const float* b = (const float*)d_in[2];   // [4096]
  const float* A = (const float*)d_in[3];   // [4096,8]
  const float* Bm = (const float*)d_in[4];  // [8,4096]
  // d_in[5] = log_K : K cancels analytically, unused.
  float* out = (float*)d_out;

  char* ws = (char*)d_ws;
  __bf16* Xb = (__bf16*)ws;                                    // 64 MB
  __bf16* Wb = (__bf16*)(ws + (size_t)64 * 1024 * 1024);       // 32 MB
  float* U = (float*)(ws + (size_t)96 * 1024 * 1024);          // 256 KB
  float* G = (float*)(ws + (size_t)96 * 1024 * 1024 + 256 * 1024);

  k_prep<<<1 + 8192 + 8192, 256, 0, stream>>>(x, W, A, Bm, Xb, Wb, U, G);
  k_gemm<<<(MR / BM) * (DD / BN), 512, 0, stream>>>(Xb, Wb, b, U, G, Bm, out);
}

// Round 10
// 303.382 us; speedup vs baseline: 8.8097x; 1.1846x over previous
//
#include <hip/hip_runtime.h>
#include <hip/hip_bf16.h>

// HypLoRA: out = x@W^T + b + 2 * scale2(row) * (u(row) @ B)
//   u(row)    = s1 * (x_row @ A), s1 = min(||x||,1.5)/max(||x||,EPS)
//   scale2    = min(n2,1.5)/max(n2,EPS),  n2^2 = u^T (B B^T) u
// K = clip(exp(log_K),...) cancels identically in log(exp(.)) at origin.
//
// Launch 1 (k_prep): G | x-section 4 ROWS PER BLOCK (A-table reuse x4: cuts
//   the A gather from 1GB to 256MB of L2 traffic) | W->bf16.
// Launch 2 (k_gemm): round-9 kernel unchanged (246us, MfmaUtil 51%).
// Round-7 lesson: launch_bounds(512,4) spills acc (7.5GB scratch). Keep (512,2).
// Round-8 lesson: lane-consecutive d is mandatory for the A gather.
// Rounds 6/8/9 lesson: intra-phase scheduling is exhausted; GEMM phase floor
//   is LDS-BW-tied (24KB/wave/K-tile ~= 79B/cyc/CU vs 85 measured ceiling).

#define DD 4096
#define MR 8192
#define BM 256
#define BN 256
#define BK 64

typedef float f32x4 __attribute__((ext_vector_type(4)));
typedef __bf16 bf16x8 __attribute__((ext_vector_type(8)));

#define GLOAD_LDS16(gptr, lptr)                                                        \
  __builtin_amdgcn_global_load_lds((const __attribute__((address_space(1))) void*)(gptr), \
                                   (__attribute__((address_space(3))) void*)(lptr), 16, 0, 0)

__device__ __forceinline__ __bf16 f2bf(float f) { return (__bf16)f; }

// ---------------- fused prep ----------------
// bid 0                  : G = B B^T (8x8)
// bid [1, 1+2048)        : rows 4*(bid-1)..+3: u = s1*(x@A); Xb = bf16(x)
// bid [1+2048, 1+10240)  : W -> bf16
__global__ __launch_bounds__(256) void k_prep(const float* __restrict__ x,
                                              const float* __restrict__ W,
                                              const float* __restrict__ A,
                                              const float* __restrict__ Bm,
                                              __bf16* __restrict__ Xb,
                                              __bf16* __restrict__ Wb,
                                              float* __restrict__ U,
                                              float* __restrict__ G) {
  int bid = blockIdx.x;
  int t = threadIdx.x;
  int lane = t & 63, wid = t >> 6;

  if (bid == 0) {
    float g[64];
#pragma unroll
    for (int i = 0; i < 64; ++i) g[i] = 0.f;
    for (int d = t; d < DD; d += 256) {
      float br[8];
#pragma unroll
      for (int r = 0; r < 8; ++r) br[r] = Bm[r * DD + d];
#pragma unroll
      for (int r = 0; r < 8; ++r)
#pragma unroll
        for (int s = 0; s < 8; ++s) g[r * 8 + s] += br[r] * br[s];
    }
    __shared__ float gs[4][64];
#pragma unroll
    for (int i = 0; i < 64; ++i) {
      float v = g[i];
      for (int off = 32; off >= 1; off >>= 1) v += __shfl_down(v, off, 64);
      if (lane == 0) gs[wid][i] = v;
    }
    __syncthreads();
    if (t < 64) G[t] = gs[0][t] + gs[1][t] + gs[2][t] + gs[3][t];
  } else if (bid <= 2048) {
    // ---- 4 rows per block: load A[d] once, apply to 4 x-rows ----
    int r0 = (bid - 1) * 4;
    const float* xr0 = x + (size_t)r0 * DD;
    __bf16* xb0 = Xb + (size_t)r0 * DD;
    float nsq[4] = {0.f, 0.f, 0.f, 0.f};
    float p[4][8] = {};
#pragma unroll
    for (int i = 0; i < 16; ++i) {
      int d = t + 256 * i;
      f32x4 a0 = *reinterpret_cast<const f32x4*>(A + (size_t)d * 8);
      f32x4 a1 = *reinterpret_cast<const f32x4*>(A + (size_t)d * 8 + 4);
#pragma unroll
      for (int r = 0; r < 4; ++r) {
        float xv = xr0[(size_t)r * DD + d];
        xb0[(size_t)r * DD + d] = f2bf(xv);
        nsq[r] += xv * xv;
        p[r][0] += xv * a0[0]; p[r][1] += xv * a0[1];
        p[r][2] += xv * a0[2]; p[r][3] += xv * a0[3];
        p[r][4] += xv * a1[0]; p[r][5] += xv * a1[1];
        p[r][6] += xv * a1[2]; p[r][7] += xv * a1[3];
      }
    }
    // wave shuffle-reduce 36 values, then cross-wave via LDS
    for (int off = 32; off >= 1; off >>= 1) {
#pragma unroll
      for (int r = 0; r < 4; ++r) {
        nsq[r] += __shfl_down(nsq[r], off, 64);
#pragma unroll
        for (int q = 0; q < 8; ++q) p[r][q] += __shfl_down(p[r][q], off, 64);
      }
    }
    __shared__ float red[4][36];
    if (lane == 0) {
#pragma unroll
      for (int r = 0; r < 4; ++r) {
        red[wid][r * 9] = nsq[r];
#pragma unroll
        for (int q = 0; q < 8; ++q) red[wid][r * 9 + 1 + q] = p[r][q];
      }
    }
    __syncthreads();
    if (t < 4) {  // thread t finalizes row r0+t
      float ns = red[0][t * 9] + red[1][t * 9] + red[2][t * 9] + red[3][t * 9];
      float u[8];
#pragma unroll
      for (int q = 0; q < 8; ++q)
        u[q] = red[0][t * 9 + 1 + q] + red[1][t * 9 + 1 + q] +
               red[2][t * 9 + 1 + q] + red[3][t * 9 + 1 + q];
      float n = sqrtf(ns);
      float s1 = fminf(n, 1.5f) / fmaxf(n, 1e-7f);
#pragma unroll
      for (int q = 0; q < 8; ++q) U[(size_t)(r0 + t) * 8 + q] = s1 * u[q];
    }
  } else {
    int i = (bid - 2049) * 256 + t;  // 8192 blocks cover 16.78M elems
    const f32x4* s = reinterpret_cast<const f32x4*>(W) + (size_t)i * 2;
    f32x4 v0 = s[0], v1 = s[1];
    bf16x8 o;
    o[0] = f2bf(v0[0]); o[1] = f2bf(v0[1]); o[2] = f2bf(v0[2]); o[3] = f2bf(v0[3]);
    o[4] = f2bf(v1[0]); o[5] = f2bf(v1[1]); o[6] = f2bf(v1[2]); o[7] = f2bf(v1[3]);
    reinterpret_cast<bf16x8*>(Wb)[i] = o;
  }
}

// ---------------- main GEMM (round-9, unchanged) ----------------
__global__ __launch_bounds__(512, 2) void k_gemm(const __bf16* __restrict__ Xb,
                                                 const __bf16* __restrict__ Wb,
                                                 const float* __restrict__ bias,
                                                 const float* __restrict__ U,
                                                 const float* __restrict__ G,
                                                 const float* __restrict__ Bm,
                                                 float* __restrict__ out) {
  __shared__ union {
    char raw[131072];
    struct { float cs[256][8]; float bs2[8][256]; } epi;
  } sm;
  char* smc = sm.raw;

  const int nwg = (MR / BM) * (DD / BN);  // 512, %8==0 -> bijective swizzle
  int wg = ((int)blockIdx.x % 8) * (nwg / 8) + (int)blockIdx.x / 8;
  int tm = wg / (DD / BN);
  int tn = wg % (DD / BN);
  int row0 = tm * BM, col0 = tn * BN;

  int t = threadIdx.x;
  int lane = t & 63, wid = t >> 6;
  int wm = wid >> 2, wn = wid & 3;  // 2x4 waves, each owns 128x64 of C
  int fr = lane & 15;
  int hi = lane >> 4;
  int sw = (fr >> 1) & 3;  // read-side swizzle key

  f32x4 acc[8][4] = {};
  bf16x8 aA[4], aB[4], bA[4], bB[4];

  auto STAGE = [&](const __bf16* mat, int rowbase, int tau, int ks, int ldsOff) {
    int j = (t & 3) ^ ((t >> 3) & 3);
    int kk = ((tau & 63) << 6) + (ks << 5) + (j << 3);
    const __bf16* src = mat + (size_t)(rowbase + (t >> 2)) * DD + kk;
    char* dst = smc + ldsOff + t * 16;
    GLOAD_LDS16(src, dst);
    GLOAD_LDS16(src + (size_t)128 * DD, dst + 8192);
  };

#define LDA(dst, buf, ks, mbase)                                                \
  _Pragma("unroll") for (int j = 0; j < 4; ++j) dst[j] =                        \
      *reinterpret_cast<const bf16x8*>(smc + (buf)*65536 + 16384 + (ks)*32768 + \
                                       (wm * 128 + ((mbase) + j) * 16 + fr) * 64 + \
                                       ((hi ^ sw) << 4));
#define LDB(dst, buf, ks)                                                       \
  _Pragma("unroll") for (int j = 0; j < 4; ++j) dst[j] =                        \
      *reinterpret_cast<const bf16x8*>(smc + (buf)*65536 + (ks)*32768 +         \
                                       (wn * 64 + j * 16 + fr) * 64 +           \
                                       ((hi ^ sw) << 4));
#define MMQ(aset, bset, mbase)                                                  \
  __builtin_amdgcn_s_setprio(1);                                                \
  _Pragma("unroll") for (int j = 0; j < 4; ++j)                                 \
      _Pragma("unroll") for (int n = 0; n < 4; ++n)                             \
          acc[(mbase) + j][n] = __builtin_amdgcn_mfma_f32_16x16x32_bf16(        \
              aset[j], bset[n], acc[(mbase) + j][n], 0, 0, 0);                  \
  __builtin_amdgcn_s_setprio(0);
#define BAR() __builtin_amdgcn_s_barrier()
#define VM6() asm volatile("s_waitcnt vmcnt(6)" ::: "memory")
#define SGB_PIN(nreads)                                      \
  __builtin_amdgcn_sched_group_barrier(0x100, (nreads), 0);  \
  __builtin_amdgcn_sched_group_barrier(0x8, 16, 0)

  // -------- prologue: tile0 all 4 regions, tile1 first 3 --------
  STAGE(Wb, col0, 0, 0, 0);
  STAGE(Xb, row0, 0, 0, 16384);
  STAGE(Wb, col0, 0, 1, 32768);
  STAGE(Xb, row0, 0, 1, 49152);
  asm volatile("s_waitcnt vmcnt(4)" ::: "memory");
  STAGE(Wb, col0, 1, 0, 65536 + 0);
  STAGE(Xb, row0, 1, 0, 65536 + 16384);
  STAGE(Wb, col0, 1, 1, 65536 + 32768);
  VM6();  // tile0 fully landed
  BAR();
  LDA(aA, 0, 0, 0);
  LDB(bA, 0, 0);

  for (int i = 0; i < DD / BK / 2; ++i) {
    int T = 2 * i;
    STAGE(Xb, row0, T + 1, 1, 65536 + 49152);
    BAR();
    LDA(aB, 0, 0, 4);
    MMQ(aA, bA, 0);
    SGB_PIN(4);
    BAR();
    STAGE(Wb, col0, T + 2, 0, 0);
    BAR();
    LDA(aA, 0, 1, 0);
    LDB(bB, 0, 1);
    MMQ(aB, bA, 4);
    SGB_PIN(8);
    BAR();
    STAGE(Xb, row0, T + 2, 0, 16384);
    BAR();
    LDA(aB, 0, 1, 4);
    MMQ(aA, bB, 0);
    SGB_PIN(4);
    BAR();
    STAGE(Wb, col0, T + 2, 1, 32768);
    BAR();
    VM6();
    LDA(aA, 1, 0, 0);
    LDB(bA, 1, 0);
    MMQ(aB, bB, 4);
    SGB_PIN(8);
    BAR();
    STAGE(Xb, row0, T + 2, 1, 49152);
    BAR();
    LDA(aB, 1, 0, 4);
    MMQ(aA, bA, 0);
    SGB_PIN(4);
    BAR();
    STAGE(Wb, col0, T + 3, 0, 65536 + 0);
    BAR();
    LDA(aA, 1, 1, 0);
    LDB(bB, 1, 1);
    MMQ(aB, bA, 4);
    SGB_PIN(8);
    BAR();
    STAGE(Xb, row0, T + 3, 0, 65536 + 16384);
    BAR();
    LDA(aB, 1, 1, 4);
    MMQ(aA, bB, 0);
    SGB_PIN(4);
    BAR();
    STAGE(Wb, col0, T + 3, 1, 65536 + 32768);
    BAR();
    VM6();
    LDA(aA, 0, 0, 0);
    LDB(bA, 0, 0);
    MMQ(aB, bB, 4);
    SGB_PIN(8);
    BAR();
  }

  // -------- epilogue: drain DMA, compute c from U,G; stage B slice --------
  asm volatile("s_waitcnt vmcnt(0)" ::: "memory");
  __syncthreads();
  {
    int rr = t >> 6, cc = (t & 63) * 4;
    *reinterpret_cast<f32x4*>(&sm.epi.bs2[rr][cc]) =
        *reinterpret_cast<const f32x4*>(Bm + (size_t)rr * DD + col0 + cc);
  }
  if (t < 256) {
    f32x4 u0 = *reinterpret_cast<const f32x4*>(U + (size_t)(row0 + t) * 8);
    f32x4 u1 = *reinterpret_cast<const f32x4*>(U + (size_t)(row0 + t) * 8 + 4);
    float u[8] = {u0[0], u0[1], u0[2], u0[3], u1[0], u1[1], u1[2], u1[3]};
    float n2sq = 0.f;
#pragma unroll
    for (int r = 0; r < 8; ++r) {
      float s = 0.f;
#pragma unroll
      for (int q = 0; q < 8; ++q) s += G[r * 8 + q] * u[q];
      n2sq += u[r] * s;
    }
    float n2 = sqrtf(fmaxf(n2sq, 0.f));
    float sc2 = 2.0f * fminf(n2, 1.5f) / fmaxf(n2, 1e-7f);
#pragma unroll
    for (int r = 0; r < 8; ++r) sm.epi.cs[t][r] = sc2 * u[r];
  }
  __syncthreads();

  int colb = col0 + wn * 64 + fr;
  float biasv[4], bcol[4][8];
#pragma unroll
  for (int n = 0; n < 4; ++n) {
    biasv[n] = bias[colb + n * 16];
#pragma unroll
    for (int r = 0; r < 8; ++r) bcol[n][r] = sm.epi.bs2[r][wn * 64 + fr + n * 16];
  }
#pragma unroll
  for (int m = 0; m < 8; ++m) {
#pragma unroll
    for (int j = 0; j < 4; ++j) {
      int rl = wm * 128 + m * 16 + hi * 4 + j;
      float c0 = sm.epi.cs[rl][0], c1 = sm.epi.cs[rl][1], c2 = sm.epi.cs[rl][2],
            c3 = sm.epi.cs[rl][3], c4 = sm.epi.cs[rl][4], c5 = sm.epi.cs[rl][5],
            c6 = sm.epi.cs[rl][6], c7 = sm.epi.cs[rl][7];
      float* orow = out + (size_t)(row0 + rl) * DD + colb;
#pragma unroll
      for (int n = 0; n < 4; ++n) {
        float delta = c0 * bcol[n][0] + c1 * bcol[n][1] + c2 * bcol[n][2] +
                      c3 * bcol[n][3] + c4 * bcol[n][4] + c5 * bcol[n][5] +
                      c6 * bcol[n][6] + c7 * bcol[n][7];
        orow[n * 16] = acc[m][n][j] + biasv[n] + delta;
      }
    }
  }
}

extern "C" void kernel_launch(void* const* d_in, const int* in_sizes, int n_in,
                              void* d_out, int out_size, void* d_ws, size_t ws_size,
                              hipStream_t stream) {
  const float* x = (const float*)d_in[0];   // [4,2048,4096]
  const float* W = (const float*)d_in[1];   // [4096,4096]
  const float* b = (const float*)d_in[2];   // [4096]
  const float* A = (const float*)d_in[3];   // [4096,8]
  const float* Bm = (const float*)d_in[4];  // [8,4096]
  // d_in[5] = log_K : K cancels analytically, unused.
  float* out = (float*)d_out;

  char* ws = (char*)d_ws;
  __bf16* Xb = (__bf16*)ws;                                    // 64 MB
  __bf16* Wb = (__bf16*)(ws + (size_t)64 * 1024 * 1024);       // 32 MB
  float* U = (float*)(ws + (size_t)96 * 1024 * 1024);          // 256 KB
  float* G = (float*)(ws + (size_t)96 * 1024 * 1024 + 256 * 1024);

  k_prep<<<1 + 2048 + 8192, 256, 0, stream>>>(x, W, A, Bm, Xb, Wb, U, G);
  k_gemm<<<(MR / BM) * (DD / BN), 512, 0, stream>>>(Xb, Wb, b, U, G, Bm, out);
}